// Round 5
// baseline (2256.383 us; speedup 1.0000x reference)
//
#include <hip/hip_runtime.h>

#define NSEQ   2000
#define CHUNK  200
#define CPAD   212          // padded row stride (dwords); rows 16B-aligned, +8 prefetch room
#define NCHUNK (NSEQ / CHUNK)
#define GATES  40
#define HID    10
#define LOG2E  1.4426950408889634f

__device__ __forceinline__ float rl(float v, int l) {
    return __uint_as_float(__builtin_amdgcn_readlane(__float_as_uint(v), l));
}
template <int CTRL>
__device__ __forceinline__ float qp(float v) {
#if __has_builtin(__builtin_amdgcn_mov_dpp)
    return __int_as_float(
        __builtin_amdgcn_mov_dpp(__float_as_int(v), CTRL, 0xF, 0xF, false));
#else
    return __int_as_float(__builtin_amdgcn_update_dpp(
        __float_as_int(v), __float_as_int(v), CTRL, 0xF, 0xF, false));
#endif
}

// One row's gate pre-activations, TRANSPOSED into LDS (dst[g*CPAD]),
// pre-scaled by m*log2e per gate type. ALL loops kept rolled (#pragma unroll 1)
// so this stays ~1 KB of code and doesn't thrash the L1I shared with the
// recurrence wave's inner loop.
__device__ __attribute__((noinline)) void compute_row(
    int r, float* dst,
    const float* __restrict__ x,
    const float* __restrict__ Wmz1, const float* __restrict__ bmz1,
    const float* __restrict__ Wmz2, const float* __restrict__ bmz2,
    const float* __restrict__ Win1, const float* __restrict__ bin1,
    const float* __restrict__ Win2, const float* __restrict__ bin2,
    const float* __restrict__ Wih,
    const float* __restrict__ bih,  const float* __restrict__ bhh)
{
    const float u = x[2 * r];
    const float w = x[2 * r + 1];
    float tr[32];
    {
        float a[32];
#pragma unroll 1
        for (int i = 0; i < 32; i++) a[i] = fmaxf(fmaf(Wmz1[i], u, bmz1[i]), 0.f);
#pragma unroll 1
        for (int o = 0; o < 16; o++) {
            float acc = bmz2[o];
#pragma unroll 1
            for (int k = 0; k < 32; k++) acc = fmaf(Wmz2[o * 32 + k], a[k], acc);
            tr[o] = fmaxf(acc, 0.f);
        }
#pragma unroll 1
        for (int i = 0; i < 32; i++) a[i] = fmaxf(fmaf(Win1[i], w, bin1[i]), 0.f);
#pragma unroll 1
        for (int o = 0; o < 16; o++) {
            float acc = bin2[o];
#pragma unroll 1
            for (int k = 0; k < 32; k++) acc = fmaf(Win2[o * 32 + k], a[k], acc);
            tr[16 + o] = fmaxf(acc, 0.f);
        }
    }
#pragma unroll 1
    for (int g = 0; g < GATES; g++) {
        float acc = bih[g] + bhh[g];
#pragma unroll 1
        for (int k = 0; k < 32; k++) acc = fmaf(Wih[g * 32 + k], tr[k], acc);
        const float sc = (g >= 20 && g < 30) ? (2.f * LOG2E) : (-LOG2E);
        dst[g * CPAD] = acc * sc;
    }
}

extern "C" __global__ void __launch_bounds__(512)
msembed_kernel(const float* __restrict__ x,
               const float* __restrict__ Wmz1, const float* __restrict__ bmz1,
               const float* __restrict__ Wmz2, const float* __restrict__ bmz2,
               const float* __restrict__ Win1, const float* __restrict__ bin1,
               const float* __restrict__ Win2, const float* __restrict__ bin2,
               const float* __restrict__ Wih,  const float* __restrict__ Whh,
               const float* __restrict__ bih,  const float* __restrict__ bhh,
               float* __restrict__ out, float* __restrict__ ws)
{
    __shared__ __align__(16) float s_xg[2][GATES * CPAD];
    const int tid = threadIdx.x;

    if (tid < CHUNK)
        compute_row(tid, &s_xg[0][tid], x,
                    Wmz1, bmz1, Wmz2, bmz2, Win1, bin1, Win2, bin2, Wih, bih, bhh);

    // lane layout: lane 4j+t = gate t (i,f,g,o) of unit j
    const int lane = tid & 63;
    const int tpe  = lane & 3;
    int j = lane >> 2;
    if (j > HID - 1) j = HID - 1;        // lanes 40-63 mirror unit 9
    const int grow = tpe * 10 + j;
    const bool valid = (tpe == 0) && (lane < 40);

    const float wsc = (tpe == 2) ? (2.f * LOG2E) : (-LOG2E);
    float whh[HID];
#pragma unroll
    for (int k = 0; k < HID; k++) whh[k] = Whh[grow * HID + k] * wsc;

    // sv = pp*rcp(1+exp2(dot)) + qq:  i: 2log2e*sigmoid, f/o: sigmoid, g: tanh
    const float pp = (tpe == 0) ? (2.f * LOG2E) : ((tpe == 2) ? -2.f : 1.f);
    const float qq = (tpe == 2) ? 1.f : 0.f;

    float h = 0.f, c2 = 0.f;             // c2 = 2log2e*c (valid lanes t=0,2)

#pragma unroll 1
    for (int ch = 0; ch < NCHUNK; ch++) {
        __syncthreads();
        if (tid < 64) {
            __builtin_amdgcn_s_setprio(3);
            const float* rowp = &s_xg[ch & 1][grow * CPAD];
            float4 cur = *reinterpret_cast<const float4*>(rowp);
            float4 nxt = *reinterpret_cast<const float4*>(rowp + 4);
            float* op = valid ? (out + ch * CHUNK * HID + j) : (ws + lane);
            const int opinc = valid ? 4 * HID : 0;
            // KEEP THIS LOOP ROLLED: a full unroll is ~10K instrs (~80KB) and
            // puts the single recurrence wave at cold-I-fetch speed.
#pragma unroll 1
            for (int s4 = 0; s4 < CHUNK; s4 += 4) {
                const float4 use = cur;
                cur = nxt;
                nxt = *reinterpret_cast<const float4*>(rowp + s4 + 8); // pad reads ok
                const float xs[4] = {use.x, use.y, use.z, use.w};
#pragma unroll
                for (int t = 0; t < 4; t++) {
                    float hs[HID];
#pragma unroll
                    for (int k = 0; k < HID; k++) hs[k] = rl(h, 4 * k);
                    float a0 = xs[t], a1 = hs[9] * whh[9];
#pragma unroll
                    for (int k = 0; k < 4; k++) {
                        a0 = fmaf(hs[2 * k],     whh[2 * k],     a0);
                        a1 = fmaf(hs[2 * k + 1], whh[2 * k + 1], a1);
                    }
                    a0 = fmaf(hs[8], whh[8], a0);
                    const float g  = a0 + a1;
                    const float sv = fmaf(
                        pp, __builtin_amdgcn_rcpf(1.f + __builtin_amdgcn_exp2f(g)), qq);
                    // 3 DPP: pair-swap (i<->g partners), bcast f, bcast o
                    const float sw = qp<0x4E>(sv);
                    const float sf = qp<0x55>(sv);
                    const float so = qp<0xFF>(sv);
                    const float pr = sv * sw;        // lanes t=0: 2log2e*sig_i*tanh_g
                    c2 = fmaf(sf, c2, pr);
                    const float th = fmaf(
                        -2.f,
                        __builtin_amdgcn_rcpf(1.f + __builtin_amdgcn_exp2f(c2)), 1.f);
                    h = so * th;
                    op[t * HID] = h;     // 10 real lanes -> out, rest -> ws
                }
                op += opinc;
            }
            __builtin_amdgcn_s_setprio(0);
        } else {
            const int idx = tid - 64;
            const int nc  = ch + 1;
            if (nc < NCHUNK && idx < CHUNK)
                compute_row(nc * CHUNK + idx, &s_xg[nc & 1][idx], x,
                            Wmz1, bmz1, Wmz2, bmz2, Win1, bin1, Win2, bin2,
                            Wih, bih, bhh);
        }
    }
}

extern "C" void kernel_launch(void* const* d_in, const int* in_sizes, int n_in,
                              void* d_out, int out_size, void* d_ws, size_t ws_size,
                              hipStream_t stream)
{
    const float* x    = (const float*)d_in[0];
    const float* Wmz1 = (const float*)d_in[1];
    const float* bmz1 = (const float*)d_in[2];
    const float* Wmz2 = (const float*)d_in[3];
    const float* bmz2 = (const float*)d_in[4];
    const float* Win1 = (const float*)d_in[5];
    const float* bin1 = (const float*)d_in[6];
    const float* Win2 = (const float*)d_in[7];
    const float* bin2 = (const float*)d_in[8];
    const float* Wih  = (const float*)d_in[9];
    const float* Whh  = (const float*)d_in[10];
    const float* bih  = (const float*)d_in[11];
    const float* bhh  = (const float*)d_in[12];
    float* out = (float*)d_out;

    hipLaunchKernelGGL(msembed_kernel, dim3(1), dim3(512), 0, stream,
                       x, Wmz1, bmz1, Wmz2, bmz2, Win1, bin1, Win2, bin2,
                       Wih, Whh, bih, bhh, out, (float*)d_ws);
}

// Round 6
// 332.289 us; speedup vs baseline: 6.7904x; 6.7904x over previous
//
#include <hip/hip_runtime.h>

#define NSEQ    2000
#define GATES   40
#define HID     10
#define XSTRIDE 2016        // xg row stride in ws (floats); 2000+12 prefetch < 2016
#define LOG2E   1.4426950408889634f

__device__ __forceinline__ float rl(float v, int l) {
    return __uint_as_float(__builtin_amdgcn_readlane(__float_as_uint(v), l));
}
template <int CTRL>
__device__ __forceinline__ float qp(float v) {
#if __has_builtin(__builtin_amdgcn_mov_dpp)
    return __int_as_float(
        __builtin_amdgcn_mov_dpp(__float_as_int(v), CTRL, 0xF, 0xF, false));
#else
    return __int_as_float(__builtin_amdgcn_update_dpp(
        __float_as_int(v), __float_as_int(v), CTRL, 0xF, 0xF, false));
#endif
}

// ---------------- kernel 1: feature+gate precompute, fully parallel ----------------
// xg[g][s] pre-scaled by m*log2e (g-gates +2log2e, i/f/o -log2e), transposed in ws.
// Loops left to -O3: full unroll batches the weight loads (R5 showed rolling them
// serializes ~2300 load latencies per thread -> 5x kernel regression).
extern "C" __global__ void __launch_bounds__(256)
xg_kernel(const float* __restrict__ x,
          const float* __restrict__ Wmz1, const float* __restrict__ bmz1,
          const float* __restrict__ Wmz2, const float* __restrict__ bmz2,
          const float* __restrict__ Win1, const float* __restrict__ bin1,
          const float* __restrict__ Win2, const float* __restrict__ bin2,
          const float* __restrict__ Wih,  const float* __restrict__ bih,
          const float* __restrict__ bhh,  float* __restrict__ xg)
{
    const int r = blockIdx.x * 256 + threadIdx.x;
    if (r >= NSEQ) return;
    const float u = x[2 * r];
    const float w = x[2 * r + 1];
    float tr[32];
    {
        float a[32];
#pragma unroll
        for (int i = 0; i < 32; i++) a[i] = fmaxf(fmaf(Wmz1[i], u, bmz1[i]), 0.f);
#pragma unroll
        for (int o = 0; o < 16; o++) {
            float acc = bmz2[o];
#pragma unroll
            for (int k = 0; k < 32; k++) acc = fmaf(Wmz2[o * 32 + k], a[k], acc);
            tr[o] = fmaxf(acc, 0.f);
        }
#pragma unroll
        for (int i = 0; i < 32; i++) a[i] = fmaxf(fmaf(Win1[i], w, bin1[i]), 0.f);
#pragma unroll
        for (int o = 0; o < 16; o++) {
            float acc = bin2[o];
#pragma unroll
            for (int k = 0; k < 32; k++) acc = fmaf(Win2[o * 32 + k], a[k], acc);
            tr[16 + o] = fmaxf(acc, 0.f);
        }
    }
#pragma unroll
    for (int g = 0; g < GATES; g++) {
        float acc = bih[g] + bhh[g];
#pragma unroll
        for (int k = 0; k < 32; k++) acc = fmaf(Wih[g * 32 + k], tr[k], acc);
        const float sc = (g >= 20 && g < 30) ? (2.f * LOG2E) : (-LOG2E);
        xg[g * XSTRIDE + r] = acc * sc;   // consecutive r in a wave -> coalesced
    }
}

// ---------------- kernel 2: recurrence, ONE wave alone on the GPU ----------------
extern "C" __global__ void __launch_bounds__(64)
rec_kernel(const float* __restrict__ Whh, const float* __restrict__ xg,
           float* __restrict__ out, float* __restrict__ dummy)
{
    // lane 4j+t = gate t (i,f,g,o) of unit j; lanes 40-63 mirror unit 9
    const int lane = threadIdx.x & 63;
    const int tpe  = lane & 3;
    int j = lane >> 2;
    if (j > HID - 1) j = HID - 1;
    const int grow = tpe * 10 + j;
    const bool valid = (tpe == 0) && (lane < 40);

    const float wsc = (tpe == 2) ? (2.f * LOG2E) : (-LOG2E);
    float whh[HID];
#pragma unroll
    for (int k = 0; k < HID; k++) whh[k] = Whh[grow * HID + k] * wsc;

    // sv = pp*rcp(1+exp2(dot)) + qq:  i: 2log2e*sigmoid, f/o: sigmoid, g: tanh
    const float pp = (tpe == 0) ? (2.f * LOG2E) : ((tpe == 2) ? -2.f : 1.f);
    const float qq = (tpe == 2) ? 1.f : 0.f;

    float h = 0.f, c2 = 0.f;             // c2 = 2log2e*c (valid lanes t=0,2)

    const float* rowp = xg + grow * XSTRIDE;
    float4 cur = *reinterpret_cast<const float4*>(rowp);
    float4 nxt = *reinterpret_cast<const float4*>(rowp + 4);
    float4 nx2 = *reinterpret_cast<const float4*>(rowp + 8);
    float* op = valid ? (out + j) : (dummy + lane);
    const int opinc = valid ? 4 * HID : 0;

#pragma unroll 1
    for (int s4 = 0; s4 < NSEQ; s4 += 4) {
        const float4 use = cur;
        cur = nxt;
        nxt = nx2;
        nx2 = *reinterpret_cast<const float4*>(rowp + s4 + 12);  // 3-deep prefetch
        const float xs[4] = {use.x, use.y, use.z, use.w};
#pragma unroll
        for (int t = 0; t < 4; t++) {
            float hs[HID];
#pragma unroll
            for (int k = 0; k < HID; k++) hs[k] = rl(h, 4 * k);
            float a0 = xs[t], a1 = hs[9] * whh[9];
#pragma unroll
            for (int k = 0; k < 4; k++) {
                a0 = fmaf(hs[2 * k],     whh[2 * k],     a0);
                a1 = fmaf(hs[2 * k + 1], whh[2 * k + 1], a1);
            }
            a0 = fmaf(hs[8], whh[8], a0);
            const float g  = a0 + a1;
            const float sv = fmaf(
                pp, __builtin_amdgcn_rcpf(1.f + __builtin_amdgcn_exp2f(g)), qq);
            // 3 DPP: pair-swap (i<->g partners), bcast f, bcast o
            const float sw = qp<0x4E>(sv);
            const float sf = qp<0x55>(sv);
            const float so = qp<0xFF>(sv);
            const float pr = sv * sw;    // lanes t=0: 2log2e*sig_i*tanh_g
            c2 = fmaf(sf, c2, pr);
            const float th = fmaf(
                -2.f, __builtin_amdgcn_rcpf(1.f + __builtin_amdgcn_exp2f(c2)), 1.f);
            h = so * th;
            op[t * HID] = h;             // 10 real lanes -> out, rest -> dummy
        }
        op += opinc;
    }
}

extern "C" void kernel_launch(void* const* d_in, const int* in_sizes, int n_in,
                              void* d_out, int out_size, void* d_ws, size_t ws_size,
                              hipStream_t stream)
{
    const float* x    = (const float*)d_in[0];
    const float* Wmz1 = (const float*)d_in[1];
    const float* bmz1 = (const float*)d_in[2];
    const float* Wmz2 = (const float*)d_in[3];
    const float* bmz2 = (const float*)d_in[4];
    const float* Win1 = (const float*)d_in[5];
    const float* bin1 = (const float*)d_in[6];
    const float* Win2 = (const float*)d_in[7];
    const float* bin2 = (const float*)d_in[8];
    const float* Wih  = (const float*)d_in[9];
    const float* Whh  = (const float*)d_in[10];
    const float* bih  = (const float*)d_in[11];
    const float* bhh  = (const float*)d_in[12];
    float* out = (float*)d_out;
    float* xgb = (float*)d_ws;                      // 40*2016*4 = 322,560 B
    float* dmy = xgb + GATES * XSTRIDE;             // 64 floats of scratch

    hipLaunchKernelGGL(xg_kernel, dim3((NSEQ + 255) / 256), dim3(256), 0, stream,
                       x, Wmz1, bmz1, Wmz2, bmz2, Win1, bin1, Win2, bin2,
                       Wih, bih, bhh, xgb);
    hipLaunchKernelGGL(rec_kernel, dim3(1), dim3(64), 0, stream,
                       Whh, xgb, out, dmy);
}

// Round 7
// 323.031 us; speedup vs baseline: 6.9850x; 1.0287x over previous
//
#include <hip/hip_runtime.h>

#define NSEQ    2000
#define CHUNK   200
#define NCHUNK  (NSEQ / CHUNK)     // 10 producer blocks
#define GATES   40
#define HID     10
#define XSTRIDE 2016               // xg row stride (floats)
#define LOG2E   1.4426950408889634f
#define MAGIC   0x1234ABCDu

__device__ __forceinline__ float rl(float v, int l) {
    return __uint_as_float(__builtin_amdgcn_readlane(__float_as_uint(v), l));
}
template <int CTRL>
__device__ __forceinline__ float qp(float v) {
#if __has_builtin(__builtin_amdgcn_mov_dpp)
    return __int_as_float(
        __builtin_amdgcn_mov_dpp(__float_as_int(v), CTRL, 0xF, 0xF, false));
#else
    return __int_as_float(__builtin_amdgcn_update_dpp(
        __float_as_int(v), __float_as_int(v), CTRL, 0xF, 0xF, false));
#endif
}

extern "C" __global__ void __launch_bounds__(256)
msembed_coop(const float* __restrict__ x,
             const float* __restrict__ Wmz1, const float* __restrict__ bmz1,
             const float* __restrict__ Wmz2, const float* __restrict__ bmz2,
             const float* __restrict__ Win1, const float* __restrict__ bin1,
             const float* __restrict__ Win2, const float* __restrict__ bin2,
             const float* __restrict__ Wih,  const float* __restrict__ Whh,
             const float* __restrict__ bih,  const float* __restrict__ bhh,
             float* __restrict__ out, float* __restrict__ ws)
{
    float*    xg    = ws;                                  // 40*2016 floats
    unsigned* flags = (unsigned*)(ws + GATES * XSTRIDE);   // NCHUNK flags
    float*    dmy   = ws + GATES * XSTRIDE + 64;           // scratch for dead lanes

    const int tid = threadIdx.x;

    if (blockIdx.x < NCHUNK) {
        // ================= producer block: 200 rows, 1 row/thread =================
        // Full unroll keeps the ~2.3K weight loads batched (R5: rolling them = 5x).
        const int b = blockIdx.x;
        const int r = b * CHUNK + tid;
        if (tid < CHUNK) {
            const float u = x[2 * r];
            const float w = x[2 * r + 1];
            float tr[32];
            {
                float a[32];
#pragma unroll
                for (int i = 0; i < 32; i++) a[i] = fmaxf(fmaf(Wmz1[i], u, bmz1[i]), 0.f);
#pragma unroll
                for (int o = 0; o < 16; o++) {
                    float acc = bmz2[o];
#pragma unroll
                    for (int k = 0; k < 32; k++) acc = fmaf(Wmz2[o * 32 + k], a[k], acc);
                    tr[o] = fmaxf(acc, 0.f);
                }
#pragma unroll
                for (int i = 0; i < 32; i++) a[i] = fmaxf(fmaf(Win1[i], w, bin1[i]), 0.f);
#pragma unroll
                for (int o = 0; o < 16; o++) {
                    float acc = bin2[o];
#pragma unroll
                    for (int k = 0; k < 32; k++) acc = fmaf(Win2[o * 32 + k], a[k], acc);
                    tr[16 + o] = fmaxf(acc, 0.f);
                }
            }
#pragma unroll
            for (int g = 0; g < GATES; g++) {
                float acc = bih[g] + bhh[g];
#pragma unroll
                for (int k = 0; k < 32; k++) acc = fmaf(Wih[g * 32 + k], tr[k], acc);
                const float sc = (g >= 20 && g < 30) ? (2.f * LOG2E) : (-LOG2E);
                xg[g * XSTRIDE + r] = acc * sc;            // coalesced in r
            }
        }
        __syncthreads();
        if (tid == 0) {
            __threadfence();                               // publish block's stores
            __hip_atomic_store(&flags[b], MAGIC, __ATOMIC_RELEASE,
                               __HIP_MEMORY_SCOPE_AGENT);
        }
        return;
    }

    // ================= recurrence block: one wave, alone on its CU =================
    if (tid >= 64) return;
    const int lane = tid;
    const int tpe  = lane & 3;          // 0=i 1=f 2=g 3=o
    int j = lane >> 2;
    if (j > HID - 1) j = HID - 1;       // lanes 40-63 mirror unit 9
    const int grow = tpe * 10 + j;
    const bool valid = (tpe == 0) && (lane < 40);

    const float wsc = (tpe == 2) ? (2.f * LOG2E) : (-LOG2E);
    float whh[HID];
#pragma unroll
    for (int k = 0; k < HID; k++) whh[k] = Whh[grow * HID + k] * wsc;

    // sv = pp*rcp(1+exp2(dot)) + qq:  i: 2log2e*sigmoid, f/o: sigmoid, g: tanh
    const float pp = (tpe == 0) ? (2.f * LOG2E) : ((tpe == 2) ? -2.f : 1.f);
    const float qq = (tpe == 2) ? 1.f : 0.f;

    float h = 0.f, c2 = 0.f;            // c2 = 2log2e*c (valid lanes t=0,2)
    const float* rowp = xg + grow * XSTRIDE;
    float* op = valid ? (out + j) : (dmy + lane);
    const int opinc = valid ? 4 * HID : 0;

#pragma unroll 1
    for (int ch = 0; ch < NCHUNK; ch++) {
        // acquire chunk ch (invalidates caches -> fresh xg reads below)
        while (__hip_atomic_load(&flags[ch], __ATOMIC_ACQUIRE,
                                 __HIP_MEMORY_SCOPE_AGENT) != MAGIC) {}
        const float* p = rowp + ch * CHUNK;
        float4 cur = *reinterpret_cast<const float4*>(p);
        float4 nxt = *reinterpret_cast<const float4*>(p + 4);
        float4 nx2 = *reinterpret_cast<const float4*>(p + 8);
#pragma unroll 1
        for (int s4 = 0; s4 < CHUNK; s4 += 4) {
            const float4 use = cur;
            cur = nxt;
            nxt = nx2;
            int m = s4 + 12;                     // clamp: never cross into
            if (m > CHUNK - 4) m = CHUNK - 4;    // an unpublished chunk
            nx2 = *reinterpret_cast<const float4*>(p + m);
            const float xs[4] = {use.x, use.y, use.z, use.w};
#pragma unroll
            for (int t = 0; t < 4; t++) {
                float hs[HID];
#pragma unroll
                for (int k = 0; k < HID; k++) hs[k] = rl(h, 4 * k);
                // consume hs in readlane order: chains start at hs[0]/hs[1]
                float a0 = fmaf(hs[0], whh[0], xs[t]);
                float a1 = hs[1] * whh[1];
#pragma unroll
                for (int k = 1; k < 5; k++) {
                    a0 = fmaf(hs[2 * k],     whh[2 * k],     a0);
                    a1 = fmaf(hs[2 * k + 1], whh[2 * k + 1], a1);
                }
                const float g  = a0 + a1;
                const float sv = fmaf(
                    pp, __builtin_amdgcn_rcpf(1.f + __builtin_amdgcn_exp2f(g)), qq);
                // 3 DPP: pair-swap (i<->g partners), bcast f, bcast o
                const float sw = qp<0x4E>(sv);
                const float sf = qp<0x55>(sv);
                const float so = qp<0xFF>(sv);
                const float pr = sv * sw;        // lanes t=0,2: i2*tanh_g
                c2 = fmaf(sf, c2, pr);
                const float th = fmaf(
                    -2.f, __builtin_amdgcn_rcpf(1.f + __builtin_amdgcn_exp2f(c2)), 1.f);
                h = so * th;
                op[t * HID] = h;                 // 10 real lanes -> out
            }
            op += opinc;
        }
    }
}

extern "C" void kernel_launch(void* const* d_in, const int* in_sizes, int n_in,
                              void* d_out, int out_size, void* d_ws, size_t ws_size,
                              hipStream_t stream)
{
    const float* x    = (const float*)d_in[0];
    const float* Wmz1 = (const float*)d_in[1];
    const float* bmz1 = (const float*)d_in[2];
    const float* Wmz2 = (const float*)d_in[3];
    const float* bmz2 = (const float*)d_in[4];
    const float* Win1 = (const float*)d_in[5];
    const float* bin1 = (const float*)d_in[6];
    const float* Win2 = (const float*)d_in[7];
    const float* bin2 = (const float*)d_in[8];
    const float* Wih  = (const float*)d_in[9];
    const float* Whh  = (const float*)d_in[10];
    const float* bih  = (const float*)d_in[11];
    const float* bhh  = (const float*)d_in[12];
    float* out = (float*)d_out;

    hipLaunchKernelGGL(msembed_coop, dim3(NCHUNK + 1), dim3(256), 0, stream,
                       x, Wmz1, bmz1, Wmz2, bmz2, Win1, bin1, Win2, bin2,
                       Wih, Whh, bih, bhh, out, (float*)d_ws);
}

// Round 8
// 316.322 us; speedup vs baseline: 7.1332x; 1.0212x over previous
//
#include <hip/hip_runtime.h>

#define NSEQ    2000
#define CHUNK   200
#define NCHUNK  (NSEQ / CHUNK)     // 10 producer blocks
#define GATES   40
#define HID     10
#define XSTRIDE 2016               // xg row stride (floats); 2000+12 prefetch < 2016
#define LOG2E   1.4426950408889634f
#define MAGIC   0x1234ABCDu

__device__ __forceinline__ float rl(float v, int l) {
    return __uint_as_float(__builtin_amdgcn_readlane(__float_as_uint(v), l));
}
template <int CTRL>
__device__ __forceinline__ float qp(float v) {
#if __has_builtin(__builtin_amdgcn_mov_dpp)
    return __int_as_float(
        __builtin_amdgcn_mov_dpp(__float_as_int(v), CTRL, 0xF, 0xF, false));
#else
    return __int_as_float(__builtin_amdgcn_update_dpp(
        __float_as_int(v), __float_as_int(v), CTRL, 0xF, 0xF, false));
#endif
}

extern "C" __global__ void __launch_bounds__(256)
msembed_coop(const float* __restrict__ x,
             const float* __restrict__ Wmz1, const float* __restrict__ bmz1,
             const float* __restrict__ Wmz2, const float* __restrict__ bmz2,
             const float* __restrict__ Win1, const float* __restrict__ bin1,
             const float* __restrict__ Win2, const float* __restrict__ bin2,
             const float* __restrict__ Wih,  const float* __restrict__ Whh,
             const float* __restrict__ bih,  const float* __restrict__ bhh,
             float* __restrict__ out, float* __restrict__ ws)
{
    float*    xg    = ws;                                  // 40*2016 floats
    unsigned* flags = (unsigned*)(ws + GATES * XSTRIDE);   // NCHUNK flags
    float*    dmy   = ws + GATES * XSTRIDE + 64;           // scratch for dead lanes

    const int tid = threadIdx.x;

    if (blockIdx.x < NCHUNK) {
        // ================= producer block: 200 rows, 1 row/thread =================
        // Full unroll keeps the ~2.3K weight loads batched (R5: rolling them = 5x).
        const int b = blockIdx.x;
        const int r = b * CHUNK + tid;
        if (tid < CHUNK) {
            const float u = x[2 * r];
            const float w = x[2 * r + 1];
            float tr[32];
            {
                float a[32];
#pragma unroll
                for (int i = 0; i < 32; i++) a[i] = fmaxf(fmaf(Wmz1[i], u, bmz1[i]), 0.f);
#pragma unroll
                for (int o = 0; o < 16; o++) {
                    float acc = bmz2[o];
#pragma unroll
                    for (int k = 0; k < 32; k++) acc = fmaf(Wmz2[o * 32 + k], a[k], acc);
                    tr[o] = fmaxf(acc, 0.f);
                }
#pragma unroll
                for (int i = 0; i < 32; i++) a[i] = fmaxf(fmaf(Win1[i], w, bin1[i]), 0.f);
#pragma unroll
                for (int o = 0; o < 16; o++) {
                    float acc = bin2[o];
#pragma unroll
                    for (int k = 0; k < 32; k++) acc = fmaf(Win2[o * 32 + k], a[k], acc);
                    tr[16 + o] = fmaxf(acc, 0.f);
                }
            }
#pragma unroll
            for (int g = 0; g < GATES; g++) {
                float acc = bih[g] + bhh[g];
#pragma unroll
                for (int k = 0; k < 32; k++) acc = fmaf(Wih[g * 32 + k], tr[k], acc);
                const float sc = (g >= 20 && g < 30) ? (2.f * LOG2E) : (-LOG2E);
                xg[g * XSTRIDE + r] = acc * sc;            // coalesced in r
            }
        }
        __syncthreads();
        if (tid == 0) {
            __threadfence();                               // publish block's stores
            __hip_atomic_store(&flags[b], MAGIC, __ATOMIC_RELEASE,
                               __HIP_MEMORY_SCOPE_AGENT);
        }
        return;
    }

    // ================= recurrence block: one wave, alone on its CU =================
    if (tid >= 64) return;

    // ---- wait ONCE for all producers, then run the 2000-step loop clean ----
    // (producers finish in ~5 us; per-chunk handshakes cost ~40 us in R7)
    for (int b = 0; b < NCHUNK; b++)
        while (__hip_atomic_load(&flags[b], __ATOMIC_ACQUIRE,
                                 __HIP_MEMORY_SCOPE_AGENT) != MAGIC) {}

    const int lane = tid;
    const int tpe  = lane & 3;          // 0=i 1=f 2=g 3=o
    int j = lane >> 2;
    if (j > HID - 1) j = HID - 1;       // lanes 40-63 mirror unit 9
    const int grow = tpe * 10 + j;
    const bool valid = (tpe == 0) && (lane < 40);

    const float wsc = (tpe == 2) ? (2.f * LOG2E) : (-LOG2E);
    float whh[HID];
#pragma unroll
    for (int k = 0; k < HID; k++) whh[k] = Whh[grow * HID + k] * wsc;

    // sv = pp*rcp(1+exp2(dot)) + qq:  i: 2log2e*sigmoid, f/o: sigmoid, g: tanh
    const float pp = (tpe == 0) ? (2.f * LOG2E) : ((tpe == 2) ? -2.f : 1.f);
    const float qq = (tpe == 2) ? 1.f : 0.f;

    float h = 0.f, c2 = 0.f;            // c2 = 2log2e*c (valid lanes t=0,2)
    const float* rowp = xg + grow * XSTRIDE;
    float* op = valid ? (out + j) : (dmy + lane);
    const int opinc = valid ? 4 * HID : 0;

    float4 cur = *reinterpret_cast<const float4*>(rowp);
    float4 nxt = *reinterpret_cast<const float4*>(rowp + 4);
    float4 nx2 = *reinterpret_cast<const float4*>(rowp + 8);

#pragma unroll 1
    for (int s4 = 0; s4 < NSEQ; s4 += 4) {
        const float4 use = cur;
        cur = nxt;
        nxt = nx2;
        nx2 = *reinterpret_cast<const float4*>(rowp + s4 + 12);  // 3-deep, no clamp
        const float xs[4] = {use.x, use.y, use.z, use.w};
#pragma unroll
        for (int t = 0; t < 4; t++) {
            float hs[HID];
#pragma unroll
            for (int k = 0; k < HID; k++) hs[k] = rl(h, 4 * k);
            // consume hs in readlane order: chains start at hs[0]/hs[1]
            float a0 = fmaf(hs[0], whh[0], xs[t]);
            float a1 = hs[1] * whh[1];
#pragma unroll
            for (int k = 1; k < 5; k++) {
                a0 = fmaf(hs[2 * k],     whh[2 * k],     a0);
                a1 = fmaf(hs[2 * k + 1], whh[2 * k + 1], a1);
            }
            const float g  = a0 + a1;
            const float sv = fmaf(
                pp, __builtin_amdgcn_rcpf(1.f + __builtin_amdgcn_exp2f(g)), qq);
            // 3 DPP: pair-swap (i<->g partners), bcast f, bcast o
            const float sw = qp<0x4E>(sv);
            const float sf = qp<0x55>(sv);
            const float so = qp<0xFF>(sv);
            const float pr = sv * sw;    // lanes t=0,2: i2*tanh_g
            c2 = fmaf(sf, c2, pr);
            const float th = fmaf(
                -2.f, __builtin_amdgcn_rcpf(1.f + __builtin_amdgcn_exp2f(c2)), 1.f);
            h = so * th;
            op[t * HID] = h;             // 10 real lanes -> out, rest -> dmy
        }
        op += opinc;
    }
}

extern "C" void kernel_launch(void* const* d_in, const int* in_sizes, int n_in,
                              void* d_out, int out_size, void* d_ws, size_t ws_size,
                              hipStream_t stream)
{
    const float* x    = (const float*)d_in[0];
    const float* Wmz1 = (const float*)d_in[1];
    const float* bmz1 = (const float*)d_in[2];
    const float* Wmz2 = (const float*)d_in[3];
    const float* bmz2 = (const float*)d_in[4];
    const float* Win1 = (const float*)d_in[5];
    const float* bin1 = (const float*)d_in[6];
    const float* Win2 = (const float*)d_in[7];
    const float* bin2 = (const float*)d_in[8];
    const float* Wih  = (const float*)d_in[9];
    const float* Whh  = (const float*)d_in[10];
    const float* bih  = (const float*)d_in[11];
    const float* bhh  = (const float*)d_in[12];
    float* out = (float*)d_out;

    hipLaunchKernelGGL(msembed_coop, dim3(NCHUNK + 1), dim3(256), 0, stream,
                       x, Wmz1, bmz1, Wmz2, bmz2, Win1, bin1, Win2, bin2,
                       Wih, Whh, bih, bhh, out, (float*)d_ws);
}